// Round 9
// baseline (81.807 us; speedup 1.0000x reference)
//
#include <hip/hip_runtime.h>

// NCC loss (B=2, C=1, 160^3 f32, 9^3 box window).
// pass_z : products + 4-wide sliding z-window -> fp8 bufA [b][z][y][f][x].
//          CHZ=5 (1600 blocks) — the empirically fast config from R5.
// pass_x : streaming 9-wide x-window on fp8 rows (in-lane halo, prefix sums)
//          bufA -> bufB. One shot per thread, no sliding state.
// pass_y : thin y-slide over xz-windowed fp8 rows + cc + reduction.
// finalize: deterministic reduce.

typedef float floatx2 __attribute__((ext_vector_type(2)));

constexpr int W = 160, H = 160, D = 160;
constexpr int SLICE = W * H;
constexpr int NVOX  = W * H * D;
constexpr int BATCH = 2;
constexpr int FROW  = 5 * W;           // 800 B per (b,z,y) row-group
constexpr float RW  = 1.0f / 729.0f;

// pass_z geometry (R5-proven: CHZ=5, 1600 blocks, ~16 us)
constexpr int TPB_Z = 256;
constexpr int XGZ   = W / 4;                     // 40
constexpr int CHZ   = 5, NCHZ = D / CHZ;         // 32 z-chunks
constexpr int NTH_Z = BATCH * XGZ * H * NCHZ;    // 409,600
constexpr int NBLK_Z = NTH_Z / TPB_Z;            // 1600

// pass_x geometry: one thread per 8-x octet, one shot
constexpr int TPB_X = 256;
constexpr int XGY   = W / 8;                     // 20
constexpr int NTH_X = BATCH * D * H * XGY;       // 1,024,000
constexpr int NBLK_X = NTH_X / TPB_X;            // 4000

// pass_y geometry (R7/R8-proven: ~18 us)
constexpr int TPB_Y = 256;
constexpr int CHY   = 2, NCHY = H / CHY;         // 80 y-chunks
constexpr int NTH_Y = BATCH * D * NCHY * XGY;    // 512,000
constexpr int NBLK_Y = NTH_Y / TPB_Y;            // 2000

// ---- fp8 helpers (HW cvt, OCP e4m3) --------------------------------------
__device__ inline unsigned int pk4(float a, float b, float c, float d) {
    unsigned int u = 0;
    u = __builtin_amdgcn_cvt_pk_fp8_f32(a, b, u, false);
    u = __builtin_amdgcn_cvt_pk_fp8_f32(c, d, u, true);
    return u;
}
__device__ inline void up8(uint2 v, float* o) {
    floatx2 t;
    t = __builtin_amdgcn_cvt_pk_f32_fp8(v.x, false); o[0] = t[0]; o[1] = t[1];
    t = __builtin_amdgcn_cvt_pk_f32_fp8(v.x, true);  o[2] = t[0]; o[3] = t[1];
    t = __builtin_amdgcn_cvt_pk_f32_fp8(v.y, false); o[4] = t[0]; o[5] = t[1];
    t = __builtin_amdgcn_cvt_pk_f32_fp8(v.y, true);  o[6] = t[0]; o[7] = t[1];
}

// ---- pass 1: products + sliding window-sum along z -----------------------
__global__ __launch_bounds__(TPB_Z) void pass_z(const float* __restrict__ I,
                                                const float* __restrict__ J,
                                                unsigned char* __restrict__ outA) {
    int t = blockIdx.x * TPB_Z + threadIdx.x;
    int xg = t % XGZ;
    int y  = (t / XGZ) % H;
    int c  = (t / (XGZ * H)) % NCHZ;
    int b  = t / (XGZ * H * NCHZ);
    int x0 = xg * 4;
    const float* Ib = I + (size_t)b * NVOX + y * W + x0;
    const float* Jb = J + (size_t)b * NVOX + y * W + x0;
    unsigned char* ob = outA + ((size_t)b * D * H + y) * FROW + x0;

    float s[5][4];
#pragma unroll
    for (int f = 0; f < 5; ++f)
#pragma unroll
        for (int i = 0; i < 4; ++i) s[f][i] = 0.f;

    auto addS = [&](int zz) {
        float4 a = *(const float4*)(Ib + (size_t)zz * SLICE);
        float4 bb = *(const float4*)(Jb + (size_t)zz * SLICE);
        float av[4] = {a.x, a.y, a.z, a.w};
        float bv[4] = {bb.x, bb.y, bb.z, bb.w};
#pragma unroll
        for (int i = 0; i < 4; ++i) {
            float x = av[i], yv = bv[i];
            s[0][i] += x; s[1][i] += yv;
            s[2][i] += x * x; s[3][i] += yv * yv; s[4][i] += x * yv;
        }
    };

    int z0 = c * CHZ;
    for (int zz = (z0 - 4 < 0 ? 0 : z0 - 4); zz <= z0 + 4; ++zz) addS(zz);

#pragma unroll
    for (int dz = 0; dz < CHZ; ++dz) {
        int z = z0 + dz;
        int za = z + 5, zs = z - 4;
        bool ha = za < D, hs = zs >= 0;
        float4 Az = ha ? *(const float4*)(Ib + (size_t)za * SLICE) : make_float4(0.f, 0.f, 0.f, 0.f);
        float4 Bz = ha ? *(const float4*)(Jb + (size_t)za * SLICE) : make_float4(0.f, 0.f, 0.f, 0.f);
        float4 As = hs ? *(const float4*)(Ib + (size_t)zs * SLICE) : make_float4(0.f, 0.f, 0.f, 0.f);
        float4 Bs = hs ? *(const float4*)(Jb + (size_t)zs * SLICE) : make_float4(0.f, 0.f, 0.f, 0.f);

        unsigned char* op = ob + (size_t)z * (H * FROW);
#pragma unroll
        for (int f = 0; f < 5; ++f)
            *(unsigned int*)(op + f * W) = pk4(s[f][0], s[f][1], s[f][2], s[f][3]);

        float ae[4] = {Az.x, Az.y, Az.z, Az.w};
        float be[4] = {Bz.x, Bz.y, Bz.z, Bz.w};
        float al[4] = {As.x, As.y, As.z, As.w};
        float bl[4] = {Bs.x, Bs.y, Bs.z, Bs.w};
#pragma unroll
        for (int i = 0; i < 4; ++i) {
            s[0][i] += ae[i] - al[i];
            s[1][i] += be[i] - bl[i];
            s[2][i] += ae[i] * ae[i] - al[i] * al[i];
            s[3][i] += be[i] * be[i] - bl[i] * bl[i];
            s[4][i] += ae[i] * be[i] - al[i] * bl[i];
        }
    }
}

// ---- pass 2: streaming 9-wide x-window on fp8 rows -----------------------
__global__ __launch_bounds__(TPB_X) void pass_x(const unsigned char* __restrict__ A,
                                                unsigned char* __restrict__ B) {
    int t = blockIdx.x * TPB_X + threadIdx.x;
    int xg = t % XGY;
    int row = t / XGY;           // (b*D+z)*H + y, dense
    int x0 = xg * 8;
    const unsigned char* rp = A + (size_t)row * FROW + x0;
    unsigned char* op = B + (size_t)row * FROW + x0;
    bool hasL = xg > 0, hasR = xg < XGY - 1;

#pragma unroll
    for (int f = 0; f < 5; ++f) {
        uint2 cl = hasL ? *(const uint2*)(rp + f * W - 8) : make_uint2(0u, 0u);
        uint2 cc = *(const uint2*)(rp + f * W);
        uint2 cr = hasR ? *(const uint2*)(rp + f * W + 8) : make_uint2(0u, 0u);
        float v[24];
        up8(cl, v); up8(cc, v + 8); up8(cr, v + 16);
        float P[24];
        P[0] = v[0];
#pragma unroll
        for (int k = 1; k < 24; ++k) P[k] = P[k - 1] + v[k];
        float o[8];
#pragma unroll
        for (int i = 0; i < 8; ++i) o[i] = P[i + 12] - P[i + 3];
        uint2 w;
        w.x = pk4(o[0], o[1], o[2], o[3]);
        w.y = pk4(o[4], o[5], o[6], o[7]);
        *(uint2*)(op + f * W) = w;
    }
}

// ---- pass 3: thin y-slide + cc + reduce ----------------------------------
__global__ __launch_bounds__(TPB_Y) void pass_y(const unsigned char* __restrict__ A,
                                                double* __restrict__ partials) {
    int tid = threadIdx.x;
    int t = blockIdx.x * TPB_Y + tid;
    int xg = t % XGY;
    int tup = t / XGY;
    int yc = tup % NCHY;
    int z  = (tup / NCHY) % D;
    int b  = tup / (NCHY * D);
    int x0 = xg * 8;
    const unsigned char* __restrict__ base =
        A + (size_t)(b * D + z) * H * FROW + x0;
    int y0 = yc * CHY;

    float s[5][8];
#pragma unroll
    for (int f = 0; f < 5; ++f)
#pragma unroll
        for (int i = 0; i < 8; ++i) s[f][i] = 0.f;

    int ylo = y0 - 4 < 0 ? 0 : y0 - 4;
    int yhi = y0 + 4 > H - 1 ? H - 1 : y0 + 4;
    for (int yy = ylo; yy <= yhi; ++yy) {
        const unsigned char* rp = base + (size_t)yy * FROW;
#pragma unroll
        for (int f = 0; f < 5; ++f) {
            uint2 v = *(const uint2*)(rp + f * W);
            float u[8]; up8(v, u);
#pragma unroll
            for (int i = 0; i < 8; ++i) s[f][i] += u[i];
        }
    }

    double acc = 0.0;
#pragma unroll
    for (int dy = 0; dy < CHY; ++dy) {
        int ye = y0 + dy + 5, yl = y0 + dy - 4;
        bool he = ye < H, hl = yl >= 0;
        uint2 pe[5], pl[5];
        const unsigned char* pre = base + (size_t)(he ? ye : 0) * FROW;
        const unsigned char* prl = base + (size_t)(hl ? yl : 0) * FROW;
#pragma unroll
        for (int f = 0; f < 5; ++f) {
            pe[f] = he ? *(const uint2*)(pre + f * W) : make_uint2(0u, 0u);
            pl[f] = hl ? *(const uint2*)(prl + f * W) : make_uint2(0u, 0u);
        }

        float rowcc = 0.f;
#pragma unroll
        for (int i = 0; i < 8; ++i) {
            float Is = s[0][i], Js = s[1][i];
            float I2s = s[2][i], J2s = s[3][i], IJs = s[4][i];
            float tI = RW * Is;
            float cross = __builtin_fmaf(-tI, Js, IJs);
            float Iv    = __builtin_fmaf(-tI, Is, I2s);
            float Jv    = __builtin_fmaf(-(RW * Js), Js, J2s);
            float den   = __builtin_fmaf(Iv, Jv, 1e-5f);
            rowcc = __builtin_fmaf(cross * cross, __builtin_amdgcn_rcpf(den), rowcc);
        }
        acc += (double)rowcc;

#pragma unroll
        for (int f = 0; f < 5; ++f) {
            float ue[8], ul[8];
            up8(pe[f], ue); up8(pl[f], ul);
#pragma unroll
            for (int i = 0; i < 8; ++i) s[f][i] += ue[i] - ul[i];
        }
    }

    // deterministic block reduction
#pragma unroll
    for (int off = 32; off > 0; off >>= 1) acc += __shfl_down(acc, off);
    __shared__ double sm[TPB_Y / 64];
    if ((tid & 63) == 0) sm[tid >> 6] = acc;
    __syncthreads();
    if (tid == 0) {
        double tt = 0.0;
#pragma unroll
        for (int i = 0; i < TPB_Y / 64; ++i) tt += sm[i];
        partials[blockIdx.x] = tt;
    }
}

// ---- final deterministic reduce ------------------------------------------
__global__ __launch_bounds__(256) void finalize(const double* __restrict__ p,
                                                float* __restrict__ out) {
    double v = 0.0;
    for (int i = threadIdx.x; i < NBLK_Y; i += 256) v += p[i];
#pragma unroll
    for (int off = 32; off > 0; off >>= 1) v += __shfl_down(v, off);
    __shared__ double sm[4];
    int lane = threadIdx.x & 63, wid = threadIdx.x >> 6;
    if (lane == 0) sm[wid] = v;
    __syncthreads();
    if (threadIdx.x == 0) {
        double tt = 0.0;
#pragma unroll
        for (int i = 0; i < 4; ++i) tt += sm[i];
        out[0] = (float)(1.0 - tt / (double)((double)BATCH * (double)NVOX));
    }
}

extern "C" void kernel_launch(void* const* d_in, const int* in_sizes, int n_in,
                              void* d_out, int out_size, void* d_ws, size_t ws_size,
                              hipStream_t stream) {
    const float* I = (const float*)d_in[0];
    const float* J = (const float*)d_in[1];
    float* out = (float*)d_out;

    // ws: bufA (41 MB fp8) | bufB (41 MB fp8) | partials (NBLK_Y f64)
    size_t bufsz = ((size_t)BATCH * 5 * NVOX + 255) / 256 * 256;
    unsigned char* bufA = (unsigned char*)d_ws;
    unsigned char* bufB = bufA + bufsz;
    double* partials = (double*)(bufB + bufsz);

    pass_z<<<NBLK_Z, TPB_Z, 0, stream>>>(I, J, bufA);
    pass_x<<<NBLK_X, TPB_X, 0, stream>>>(bufA, bufB);
    pass_y<<<NBLK_Y, TPB_Y, 0, stream>>>(bufB, partials);
    finalize<<<1, 256, 0, stream>>>(partials, out);
}

// Round 10
// 63.797 us; speedup vs baseline: 1.2823x; 1.2823x over previous
//
#include <hip/hip_runtime.h>

// NCC loss (B=2, C=1, 160^3 f32, 9^3 box window). Two passes + reduce.
// pass_zx: products + 4-wide sliding z-window in regs; per produced z the
//          x-window is applied via LDS row staging (zero-padded halo,
//          conflict-free contiguous b128 pattern) -> fp8 bufA [b][z][y][f][x].
// pass_y : thin y-slide over xz-windowed fp8 rows + cc + reduction.
// finalize: deterministic reduce. Unique footprint ~108 MB (L3-resident).

typedef float floatx2 __attribute__((ext_vector_type(2)));

constexpr int W = 160, H = 160, D = 160;
constexpr int SLICE = W * H;
constexpr int NVOX  = W * H * D;
constexpr int BATCH = 2;
constexpr int FROW  = 5 * W;             // 800 B per (b,z,y) row-group
constexpr float RW  = 1.0f / 729.0f;

// pass_zx geometry
constexpr int TPB_ZX = 320;              // 8 rows x 40 x-groups
constexpr int ROWS_PB = 8;
constexpr int XGZ   = W / 4;             // 40
constexpr int CHZ   = 5, NCHZ = D / CHZ; // 32 z-chunks
constexpr int NTUP_ZX = BATCH * NCHZ * H;        // 10,240 (b,c,y) rows
constexpr int NBLK_ZX = NTUP_ZX / ROWS_PB;       // 1280
constexpr int LROW  = 168;               // 4 zero-pad | 160 | 4 zero-pad

// pass_y geometry (proven thin config)
constexpr int TPB_Y = 256;
constexpr int XGY   = W / 8;             // 20
constexpr int CHY   = 2, NCHY = H / CHY; // 80
constexpr int NTH_Y = BATCH * D * NCHY * XGY;    // 512,000
constexpr int NBLK_Y = NTH_Y / TPB_Y;            // 2000

// ---- fp8 helpers (HW cvt, OCP e4m3) --------------------------------------
__device__ inline unsigned int pk4(float a, float b, float c, float d) {
    unsigned int u = 0;
    u = __builtin_amdgcn_cvt_pk_fp8_f32(a, b, u, false);
    u = __builtin_amdgcn_cvt_pk_fp8_f32(c, d, u, true);
    return u;
}
__device__ inline void up8(uint2 v, float* o) {
    floatx2 t;
    t = __builtin_amdgcn_cvt_pk_f32_fp8(v.x, false); o[0] = t[0]; o[1] = t[1];
    t = __builtin_amdgcn_cvt_pk_f32_fp8(v.x, true);  o[2] = t[0]; o[3] = t[1];
    t = __builtin_amdgcn_cvt_pk_f32_fp8(v.y, false); o[4] = t[0]; o[5] = t[1];
    t = __builtin_amdgcn_cvt_pk_f32_fp8(v.y, true);  o[6] = t[0]; o[7] = t[1];
}

// ---- pass 1: z-window (regs) + x-window (LDS staging) --------------------
__global__ __launch_bounds__(TPB_ZX) void pass_zx(const float* __restrict__ I,
                                                  const float* __restrict__ J,
                                                  unsigned char* __restrict__ outA) {
    __shared__ float lds[ROWS_PB][5][LROW];

    int tid = threadIdx.x;
    int r  = tid / XGZ;                  // 0..7 row-in-block
    int xg = tid % XGZ;                  // 0..39
    int tuple = blockIdx.x * ROWS_PB + r;
    int y = tuple % H;
    int c = (tuple / H) % NCHZ;
    int b = tuple / (H * NCHZ);
    int x0 = xg * 4;
    const float* Ib = I + (size_t)b * NVOX + y * W + x0;
    const float* Jb = J + (size_t)b * NVOX + y * W + x0;
    unsigned char* ob = outA + ((size_t)b * D * H + y) * FROW + x0;

    // zero the halo pads once
    if (xg == 0) {
#pragma unroll
        for (int f = 0; f < 5; ++f) {
            lds[r][f][0] = 0.f; lds[r][f][1] = 0.f;
            lds[r][f][2] = 0.f; lds[r][f][3] = 0.f;
        }
    }
    if (xg == XGZ - 1) {
#pragma unroll
        for (int f = 0; f < 5; ++f) {
            lds[r][f][164] = 0.f; lds[r][f][165] = 0.f;
            lds[r][f][166] = 0.f; lds[r][f][167] = 0.f;
        }
    }

    float s[5][4];
#pragma unroll
    for (int f = 0; f < 5; ++f)
#pragma unroll
        for (int i = 0; i < 4; ++i) s[f][i] = 0.f;

    auto addS = [&](int zz) {
        float4 a = *(const float4*)(Ib + (size_t)zz * SLICE);
        float4 bb = *(const float4*)(Jb + (size_t)zz * SLICE);
        float av[4] = {a.x, a.y, a.z, a.w};
        float bv[4] = {bb.x, bb.y, bb.z, bb.w};
#pragma unroll
        for (int i = 0; i < 4; ++i) {
            float x = av[i], yv = bv[i];
            s[0][i] += x; s[1][i] += yv;
            s[2][i] += x * x; s[3][i] += yv * yv; s[4][i] += x * yv;
        }
    };

    int z0 = c * CHZ;
    for (int zz = (z0 - 4 < 0 ? 0 : z0 - 4); zz <= z0 + 4; ++zz) addS(zz);

    for (int dz = 0; dz < CHZ; ++dz) {
        int z = z0 + dz;
        int za = z + 5, zs = z - 4;
        bool ha = za < D, hs = zs >= 0;
        // issue next-tap loads early (latency hides under LDS work)
        float4 Az = ha ? *(const float4*)(Ib + (size_t)za * SLICE) : make_float4(0.f, 0.f, 0.f, 0.f);
        float4 Bz = ha ? *(const float4*)(Jb + (size_t)za * SLICE) : make_float4(0.f, 0.f, 0.f, 0.f);
        float4 As = hs ? *(const float4*)(Ib + (size_t)zs * SLICE) : make_float4(0.f, 0.f, 0.f, 0.f);
        float4 Bs = hs ? *(const float4*)(Jb + (size_t)zs * SLICE) : make_float4(0.f, 0.f, 0.f, 0.f);

        // stage own 4 z-sums per field
#pragma unroll
        for (int f = 0; f < 5; ++f)
            *(float4*)&lds[r][f][4 + x0] = make_float4(s[f][0], s[f][1], s[f][2], s[f][3]);
        __syncthreads();

        // x-window: neighborhood [x0-4, x0+7] = L(4) + own(4) + R(4)
        unsigned char* op = ob + (size_t)z * (H * FROW);
#pragma unroll
        for (int f = 0; f < 5; ++f) {
            float4 Lv = *(const float4*)&lds[r][f][x0];        // x0-4..x0-1
            float4 Rv = *(const float4*)&lds[r][f][x0 + 8];    // x0+4..x0+7
            float p0 = Lv.x;
            float p1 = p0 + Lv.y;
            float p2 = p1 + Lv.z;
            float p3 = p2 + Lv.w;
            float p4 = p3 + s[f][0];
            float p5 = p4 + s[f][1];
            float p6 = p5 + s[f][2];
            float p7 = p6 + s[f][3];
            float p8 = p7 + Rv.x;
            float p9 = p8 + Rv.y;
            float p10 = p9 + Rv.z;
            float p11 = p10 + Rv.w;
            *(unsigned int*)(op + f * W) = pk4(p8, p9 - p0, p10 - p1, p11 - p2);
        }
        __syncthreads();   // protect LDS before next dz overwrite

        // slide the z-window
        float ae[4] = {Az.x, Az.y, Az.z, Az.w};
        float be[4] = {Bz.x, Bz.y, Bz.z, Bz.w};
        float al[4] = {As.x, As.y, As.z, As.w};
        float bl[4] = {Bs.x, Bs.y, Bs.z, Bs.w};
#pragma unroll
        for (int i = 0; i < 4; ++i) {
            s[0][i] += ae[i] - al[i];
            s[1][i] += be[i] - bl[i];
            s[2][i] += ae[i] * ae[i] - al[i] * al[i];
            s[3][i] += be[i] * be[i] - bl[i] * bl[i];
            s[4][i] += ae[i] * be[i] - al[i] * bl[i];
        }
    }
}

// ---- pass 2: thin y-slide + cc + reduce ----------------------------------
__global__ __launch_bounds__(TPB_Y) void pass_y(const unsigned char* __restrict__ A,
                                                double* __restrict__ partials) {
    int tid = threadIdx.x;
    int t = blockIdx.x * TPB_Y + tid;
    int xg = t % XGY;
    int tup = t / XGY;
    int yc = tup % NCHY;
    int z  = (tup / NCHY) % D;
    int b  = tup / (NCHY * D);
    int x0 = xg * 8;
    const unsigned char* __restrict__ base =
        A + (size_t)(b * D + z) * H * FROW + x0;
    int y0 = yc * CHY;

    float s[5][8];
#pragma unroll
    for (int f = 0; f < 5; ++f)
#pragma unroll
        for (int i = 0; i < 8; ++i) s[f][i] = 0.f;

    int ylo = y0 - 4 < 0 ? 0 : y0 - 4;
    int yhi = y0 + 4 > H - 1 ? H - 1 : y0 + 4;
    for (int yy = ylo; yy <= yhi; ++yy) {
        const unsigned char* rp = base + (size_t)yy * FROW;
#pragma unroll
        for (int f = 0; f < 5; ++f) {
            uint2 v = *(const uint2*)(rp + f * W);
            float u[8]; up8(v, u);
#pragma unroll
            for (int i = 0; i < 8; ++i) s[f][i] += u[i];
        }
    }

    double acc = 0.0;
#pragma unroll
    for (int dy = 0; dy < CHY; ++dy) {
        int ye = y0 + dy + 5, yl = y0 + dy - 4;
        bool he = ye < H, hl = yl >= 0;
        uint2 pe[5], pl[5];
        const unsigned char* pre = base + (size_t)(he ? ye : 0) * FROW;
        const unsigned char* prl = base + (size_t)(hl ? yl : 0) * FROW;
#pragma unroll
        for (int f = 0; f < 5; ++f) {
            pe[f] = he ? *(const uint2*)(pre + f * W) : make_uint2(0u, 0u);
            pl[f] = hl ? *(const uint2*)(prl + f * W) : make_uint2(0u, 0u);
        }

        float rowcc = 0.f;
#pragma unroll
        for (int i = 0; i < 8; ++i) {
            float Is = s[0][i], Js = s[1][i];
            float I2s = s[2][i], J2s = s[3][i], IJs = s[4][i];
            float tI = RW * Is;
            float cross = __builtin_fmaf(-tI, Js, IJs);
            float Iv    = __builtin_fmaf(-tI, Is, I2s);
            float Jv    = __builtin_fmaf(-(RW * Js), Js, J2s);
            float den   = __builtin_fmaf(Iv, Jv, 1e-5f);
            rowcc = __builtin_fmaf(cross * cross, __builtin_amdgcn_rcpf(den), rowcc);
        }
        acc += (double)rowcc;

#pragma unroll
        for (int f = 0; f < 5; ++f) {
            float ue[8], ul[8];
            up8(pe[f], ue); up8(pl[f], ul);
#pragma unroll
            for (int i = 0; i < 8; ++i) s[f][i] += ue[i] - ul[i];
        }
    }

    // deterministic block reduction
#pragma unroll
    for (int off = 32; off > 0; off >>= 1) acc += __shfl_down(acc, off);
    __shared__ double sm[TPB_Y / 64];
    if ((tid & 63) == 0) sm[tid >> 6] = acc;
    __syncthreads();
    if (tid == 0) {
        double tt = 0.0;
#pragma unroll
        for (int i = 0; i < TPB_Y / 64; ++i) tt += sm[i];
        partials[blockIdx.x] = tt;
    }
}

// ---- final deterministic reduce ------------------------------------------
__global__ __launch_bounds__(256) void finalize(const double* __restrict__ p,
                                                float* __restrict__ out) {
    double v = 0.0;
    for (int i = threadIdx.x; i < NBLK_Y; i += 256) v += p[i];
#pragma unroll
    for (int off = 32; off > 0; off >>= 1) v += __shfl_down(v, off);
    __shared__ double sm[4];
    int lane = threadIdx.x & 63, wid = threadIdx.x >> 6;
    if (lane == 0) sm[wid] = v;
    __syncthreads();
    if (threadIdx.x == 0) {
        double tt = 0.0;
#pragma unroll
        for (int i = 0; i < 4; ++i) tt += sm[i];
        out[0] = (float)(1.0 - tt / (double)((double)BATCH * (double)NVOX));
    }
}

extern "C" void kernel_launch(void* const* d_in, const int* in_sizes, int n_in,
                              void* d_out, int out_size, void* d_ws, size_t ws_size,
                              hipStream_t stream) {
    const float* I = (const float*)d_in[0];
    const float* J = (const float*)d_in[1];
    float* out = (float*)d_out;

    // ws: bufA (41 MB fp8) | partials (NBLK_Y f64)
    size_t bufsz = ((size_t)BATCH * 5 * NVOX + 255) / 256 * 256;
    unsigned char* bufA = (unsigned char*)d_ws;
    double* partials = (double*)(bufA + bufsz);

    pass_zx<<<NBLK_ZX, TPB_ZX, 0, stream>>>(I, J, bufA);
    pass_y<<<NBLK_Y, TPB_Y, 0, stream>>>(bufA, partials);
    finalize<<<1, 256, 0, stream>>>(partials, out);
}